// Round 2
// baseline (436.971 us; speedup 1.0000x reference)
//
#include <hip/hip_runtime.h>

// Inputs: M (f32, 2048x4096), params (f32, 4096), kinds (int32, 4096).
// Output: f32, 10240x10240.
// Timing model: fixed harness overhead ~343 us/iter (1.6 GiB ws poison 267 +
// 400 MiB out poison ~65 + input restore ~11). Controllable floor: 419 MB
// write + ~34 MB cold read @ 6.36 TB/s ~= 71 us -> window floor ~414 us.
// History: R3 437.6 / R4 434.2 / R5 443.5 / R6 429.2 / R7 425.7 (fused,
// 64KB LDS, 2 blk/CU) / R8 435.9 (fused, 16KB LDS, 8 blk/CU — REGRESSED:
// higher residency let TP blocks run early, overlapping the M-copy phase ->
// L3-cold TP reads + HBM read/write mixing).
// R9: split into TWO kernels on the stream (stream order = serialization):
//   A) rows kernel — 10240 blocks, ZERO LDS, pure write streaming.
//   B) tp kernel   — 512 blocks, R7's 512x32 tile (64KB LDS), runs strictly
//      after A: M re-read is guaranteed L3-resident, no r/w mixing.
#define NN 2048              // N_NODES
#define EE 4096              // N_ELEMS
#define WW 10240             // 2*E + N columns
#define TOT_ROWS 10240       // N + 2*E rows

typedef float v4f __attribute__((ext_vector_type(4)));

#define TP_BLOCKS 512        // 512(M rows) x 32(M cols) tiles: 4 x 128

__device__ __forceinline__ void nt_store(float* p, v4f v) {
    __builtin_nontemporal_store(v, (v4f*)p);   // streamed, zero-reuse output
}

// Kernel A: one output ROW per block, fully contiguous 32-40 KB stream.
//  rows [0,N):      [copy M row | zeros]  (copy chunk = 16 KB contiguous;
//                   also warms M into L3 for the TP kernel)
//  rows [N,N+E):    [zeros | I_E]  cols [0,2E)  (-M^T owned by TP kernel)
//  rows [N+E,2E+N): zeros + z@e + y@(E+e)
__global__ __launch_bounds__(256) void rows_kernel(
    const float* __restrict__ M,
    const float* __restrict__ params,
    const int*   __restrict__ kinds,
    float*       __restrict__ out)
{
    int tid = threadIdx.x;
    int row = blockIdx.x;
    int tid4 = tid * 4;
    float* dst = out + (size_t)row * WW;
    const v4f zero = {0.f, 0.f, 0.f, 0.f};

    if (row < NN) {
        // [copy M row | zeros] — one contiguous 40 KB stream
        const float* src = M + (size_t)row * EE;
        #pragma unroll
        for (int k = 0; k < 4; ++k) {
            int off = k * 1024 + tid4;
            nt_store(dst + off, *(const v4f*)(src + off));
        }
        #pragma unroll
        for (int k = 4; k < 10; ++k)
            nt_store(dst + k * 1024 + tid4, zero);
    } else if (row < NN + EE) {
        // [zeros | I_E] over cols [0,2E)
        int e = row - NN;
        int col_y = EE + e;
        #pragma unroll
        for (int k = 0; k < 8; ++k) {
            int base = k * 1024 + tid4;
            v4f v = zero;
            #pragma unroll
            for (int j = 0; j < 4; ++j)
                if (base + j == col_y) v[j] = 1.0f;
            nt_store(dst + base, v);
        }
    } else {
        // elem rows: z at col e, y at col E+e
        int e = row - (NN + EE);
        float p = params[e];
        int kk = kinds[e];
        bool on = p > 0.0f;
        float z, y;
        if (kk == 0)      { z = -p;             y = 1.0f; }           // R
        else if (kk == 1) { z = 0.0f;           y = 1.0f; }           // IVS
        else if (kk == 2) { z = 1.0f;           y = 0.0f; }           // VC
        else              { z = on ? 0.f : 1.f; y = on ? 1.f : 0.f; } // SW
        int col_z = e, col_y = EE + e;
        #pragma unroll
        for (int k = 0; k < 10; ++k) {
            int base = k * 1024 + tid4;
            v4f v = zero;
            #pragma unroll
            for (int j = 0; j < 4; ++j) {
                if (base + j == col_z) v[j] = z;
                if (base + j == col_y) v[j] = y;
            }
            nt_store(dst + base, v);
        }
    }
}

// Kernel B: TP tile 512 M-rows x 32 M-cols -> -M^T rows [N,N+E), cols [2E,W).
// LDS t[c][rr] with XOR swizzle index c*512 + (rr ^ (c&28)):
//  - write: 8 lanes sharing rr have distinct c&28 -> distinct banks;
//    across a wave max 2-way aliasing (free per m136).
//  - read: c fixed, (rr0+i)^(c&28) = (rr0^(c&28))+i for 4-aligned rr0
//    (c&28 has no bits 0-1) -> ds_read_b128 stays contiguous.
// Each of 32 output rows receives a 2 KB contiguous chunk per pass.
// Runs strictly after rows_kernel (same stream): M reads are L3 hits.
__global__ __launch_bounds__(256) void tp_kernel(
    const float* __restrict__ M,
    float*       __restrict__ out)
{
    __shared__ __align__(16) float t[32 * 512];   // 64 KB
    int tid = threadIdx.x;
    int tpIdx = blockIdx.x;                       // [0, 512)
    int cT = (tpIdx & 127) << 5;   // M col base (output row base), 128 tiles
    int rT = (tpIdx >> 7) << 9;    // M row base (output col base), 4 tiles

    #pragma unroll
    for (int pass = 0; pass < 16; ++pass) {
        int rr = pass * 32 + (tid >> 3);          // M row within tile [0,512)
        int c0 = (tid & 7) * 4;                   // M col within tile
        v4f val = *(const v4f*)(M + (size_t)(rT + rr) * EE + cT + c0);
        #pragma unroll
        for (int i = 0; i < 4; ++i) {
            int c = c0 + i;
            t[c * 512 + (rr ^ (c & 28))] = val[i];
        }
    }
    __syncthreads();

    #pragma unroll
    for (int pass = 0; pass < 16; ++pass) {
        int e   = pass * 2 + (tid >> 7);          // output row within tile [0,32)
        int rr0 = (tid & 127) * 4;                // output col within tile [0,512)
        v4f v = *(const v4f*)(&t[e * 512 + (rr0 ^ (e & 28))]);
        v4f nv = { -v[0], -v[1], -v[2], -v[3] };
        nt_store(out + (size_t)(NN + cT + e) * WW + 2 * EE + rT + rr0, nv);
    }
}

extern "C" void kernel_launch(void* const* d_in, const int* in_sizes, int n_in,
                              void* d_out, int out_size, void* d_ws, size_t ws_size,
                              hipStream_t stream) {
    const float* M      = (const float*)d_in[0];   // f32, 2048x4096
    const float* params = (const float*)d_in[1];   // f32, 4096
    const int*   kinds  = (const int*)d_in[2];     // int32, 4096
    float*       out    = (float*)d_out;           // f32, 10240x10240

    rows_kernel<<<TOT_ROWS, 256, 0, stream>>>(M, params, kinds, out);
    tp_kernel<<<TP_BLOCKS, 256, 0, stream>>>(M, out);
}

// Round 3
// 424.726 us; speedup vs baseline: 1.0288x; 1.0288x over previous
//
#include <hip/hip_runtime.h>

// Inputs: M (f32, 2048x4096), params (f32, 4096), kinds (int32, 4096).
// Output: f32, 10240x10240.
// Timing model: fixed harness overhead ~343 us/iter (1.6 GiB ws poison 267 +
// 400 MiB out poison ~65 + input restore ~11). Controllable floor: 419 MB
// write + ~34 MB cold read @ 6.36 TB/s ~= 71 us -> window floor ~414 us.
// History: R3 437.6 / R4 434.2 / R5 443.5 / R6 429.2 / R7 425.7 (fused,
// 64KB LDS, TP at tail) / R8 435.9 (16KB LDS, 8 blk/CU) / R9 437.0 (split
// kernels, rows at 8 blk/CU). LESSON from R8+R9: row-phase occupancy above
// ~2 blocks/CU costs ~11 us — the 64KB LDS throttle is load-bearing. Keep it.
// R10: R7 structure, but TP blocks moved to the FRONT of the grid:
//  - first 512 blocks (= exactly 2/CU machine fill) do the transpose and
//    perform the one mandatory cold HBM read of M as a dense parallel burst;
//  - the 2048 copy blocks that follow then read M as L3 HITS (~200 cy,
//    trivially hidden), so the 385.9 MB row phase streams at pure-fill rate;
//  - no TP tail at the end.
#define NN 2048              // N_NODES
#define EE 4096              // N_ELEMS
#define WW 10240             // 2*E + N columns
#define TOT_ROWS 10240       // N + 2*E rows

typedef float v4f __attribute__((ext_vector_type(4)));

#define TP_BLOCKS 512        // 512(M rows) x 32(M cols) tiles: 4 x 128

__device__ __forceinline__ void nt_store(float* p, v4f v) {
    __builtin_nontemporal_store(v, (v4f*)p);   // streamed, zero-reuse output
}

// Single fused kernel. Grid = [TP blocks 0..512) ++ [row blocks ..+10240).
//  TP blocks (run FIRST — cold-read M once, machine-wide burst):
//    512x32 tile of M -> -M^T rows [N,N+E), cols [2E,W); each of 32 output
//    rows receives a 2 KB contiguous chunk per pass.
//  Row blocks: one output ROW each, fully contiguous 32-40 KB stream:
//    rows [0,N):      [copy M row | zeros]  (M read is L3-hit after TP)
//    rows [N,N+E):    [zeros | I_E]  cols [0,2E)  (-M^T owned by TP)
//    rows [N+E,2E+N): zeros + z@e + y@(E+e)
// Static 64 KB LDS throttles ALL blocks to 2/CU (8 waves) — measured optimum
// for the write stream (R7 vs R8/R9).
// Every output element is written exactly once (out re-poisoned each call).
__global__ __launch_bounds__(256) void coeff_kernel(
    const float* __restrict__ M,
    const float* __restrict__ params,
    const int*   __restrict__ kinds,
    float*       __restrict__ out)
{
    __shared__ __align__(16) float t[32 * 512];   // 64 KB (also the throttle)
    int tid = threadIdx.x;

    if (blockIdx.x < TP_BLOCKS) {
        // TP tile: 512 M-rows x 32 M-cols. LDS t[c][rr] with XOR swizzle
        // index c*512 + (rr ^ (c&28)):
        //  - write: 8 lanes sharing rr have distinct c&28 -> distinct banks;
        //    across a wave max 2-way aliasing (free per m136).
        //  - read: c fixed, (rr0+i)^(c&28) = (rr0^(c&28))+i for 4-aligned
        //    rr0 (c&28 has no bits 0-1) -> ds_read_b128 stays contiguous.
        int tpIdx = blockIdx.x;                       // [0, 512)
        int cT = (tpIdx & 127) << 5;   // M col base (output row base), 128 tiles
        int rT = (tpIdx >> 7) << 9;    // M row base (output col base), 4 tiles

        #pragma unroll
        for (int pass = 0; pass < 16; ++pass) {
            int rr = pass * 32 + (tid >> 3);          // M row within tile [0,512)
            int c0 = (tid & 7) * 4;                   // M col within tile
            v4f val = *(const v4f*)(M + (size_t)(rT + rr) * EE + cT + c0);
            #pragma unroll
            for (int i = 0; i < 4; ++i) {
                int c = c0 + i;
                t[c * 512 + (rr ^ (c & 28))] = val[i];
            }
        }
        __syncthreads();

        #pragma unroll
        for (int pass = 0; pass < 16; ++pass) {
            int e   = pass * 2 + (tid >> 7);          // output row within tile [0,32)
            int rr0 = (tid & 127) * 4;                // output col within tile [0,512)
            v4f v = *(const v4f*)(&t[e * 512 + (rr0 ^ (e & 28))]);
            v4f nv = { -v[0], -v[1], -v[2], -v[3] };
            nt_store(out + (size_t)(NN + cT + e) * WW + 2 * EE + rT + rr0, nv);
        }
    } else {
        int row = blockIdx.x - TP_BLOCKS;             // [0, 10240)
        int tid4 = tid * 4;
        float* dst = out + (size_t)row * WW;
        const v4f zero = {0.f, 0.f, 0.f, 0.f};

        if (row < NN) {
            // [copy M row | zeros] — one contiguous 40 KB stream; M is
            // L3-resident (TP blocks read it first), loads ~200 cy.
            const float* src = M + (size_t)row * EE;
            #pragma unroll
            for (int k = 0; k < 4; ++k) {
                int off = k * 1024 + tid4;
                nt_store(dst + off, *(const v4f*)(src + off));
            }
            #pragma unroll
            for (int k = 4; k < 10; ++k)
                nt_store(dst + k * 1024 + tid4, zero);
        } else if (row < NN + EE) {
            // [zeros | I_E] over cols [0,2E)
            int e = row - NN;
            int col_y = EE + e;
            #pragma unroll
            for (int k = 0; k < 8; ++k) {
                int base = k * 1024 + tid4;
                v4f v = zero;
                #pragma unroll
                for (int j = 0; j < 4; ++j)
                    if (base + j == col_y) v[j] = 1.0f;
                nt_store(dst + base, v);
            }
        } else {
            // elem rows: z at col e, y at col E+e
            int e = row - (NN + EE);
            float p = params[e];
            int kk = kinds[e];
            bool on = p > 0.0f;
            float z, y;
            if (kk == 0)      { z = -p;             y = 1.0f; }           // R
            else if (kk == 1) { z = 0.0f;           y = 1.0f; }           // IVS
            else if (kk == 2) { z = 1.0f;           y = 0.0f; }           // VC
            else              { z = on ? 0.f : 1.f; y = on ? 1.f : 0.f; } // SW
            int col_z = e, col_y = EE + e;
            #pragma unroll
            for (int k = 0; k < 10; ++k) {
                int base = k * 1024 + tid4;
                v4f v = zero;
                #pragma unroll
                for (int j = 0; j < 4; ++j) {
                    if (base + j == col_z) v[j] = z;
                    if (base + j == col_y) v[j] = y;
                }
                nt_store(dst + base, v);
            }
        }
    }
}

extern "C" void kernel_launch(void* const* d_in, const int* in_sizes, int n_in,
                              void* d_out, int out_size, void* d_ws, size_t ws_size,
                              hipStream_t stream) {
    const float* M      = (const float*)d_in[0];   // f32, 2048x4096
    const float* params = (const float*)d_in[1];   // f32, 4096
    const int*   kinds  = (const int*)d_in[2];     // int32, 4096
    float*       out    = (float*)d_out;           // f32, 10240x10240

    coeff_kernel<<<TP_BLOCKS + TOT_ROWS, 256, 0, stream>>>(M, params, kinds, out);
}